// Round 1
// baseline (2852.113 us; speedup 1.0000x reference)
//
#include <hip/hip_runtime.h>
#include <cstdint>

#define ED 256
#define D1 128
#define D2 64
#define NC 50
#define KP 52      // NC padded to multiple of 4 for float4
#define NB 4
#define NN 4096
#define R1 16      // rows per block, mlp kernel
#define TI 8       // i-rows per block, pair kernel

// ---------------- Kernel 1: MLP 256 -> 128 -> 64 -> 50, plus |z|^2 ----------------
__global__ __launch_bounds__(256) void mlp_kernel(
    const float* __restrict__ emb,
    const float* __restrict__ W1, const float* __restrict__ b1,
    const float* __restrict__ W2, const float* __restrict__ b2,
    const float* __restrict__ W3, const float* __restrict__ b3,
    float* __restrict__ z, float* __restrict__ sq)
{
    __shared__ __align__(16) float se[R1*ED];
    __shared__ __align__(16) float sh1[R1*D1];
    __shared__ __align__(16) float sh2[R1*D2];
    __shared__ __align__(16) float sz[R1*KP];
    const int t = threadIdx.x;
    const long row0 = (long)blockIdx.x * R1;

    // stage 16 embedding rows (contiguous) into LDS, float4
    {
        const float4* g4 = (const float4*)(emb + row0*ED);
        float4* s4 = (float4*)se;
        #pragma unroll
        for (int k = 0; k < (R1*ED/4)/256; k++)
            s4[t + k*256] = g4[t + k*256];
    }
    __syncthreads();

    // layer 1: each thread = one f column, 8 rows; weight column cached per d-chunk
    {
        const int f = t & (D1-1);
        const int half = t >> 7;            // 0/1: rows [half*8, half*8+8)
        float acc[8];
        const float bias = b1[f];
        #pragma unroll
        for (int rr = 0; rr < 8; rr++) acc[rr] = bias;
        for (int d = 0; d < ED; d += 4) {
            const float w0 = W1[(d+0)*D1 + f];
            const float w1 = W1[(d+1)*D1 + f];
            const float w2 = W1[(d+2)*D1 + f];
            const float w3 = W1[(d+3)*D1 + f];
            #pragma unroll
            for (int rr = 0; rr < 8; rr++) {
                const float4 e = *(const float4*)&se[(half*8+rr)*ED + d]; // wave-broadcast
                acc[rr] = fmaf(e.x, w0, acc[rr]);
                acc[rr] = fmaf(e.y, w1, acc[rr]);
                acc[rr] = fmaf(e.z, w2, acc[rr]);
                acc[rr] = fmaf(e.w, w3, acc[rr]);
            }
        }
        #pragma unroll
        for (int rr = 0; rr < 8; rr++)
            sh1[(half*8+rr)*D1 + f] = fmaxf(acc[rr], 0.0f);
    }
    __syncthreads();

    // layer 2: each thread = one f (0..63), 4 rows
    {
        const int f = t & (D2-1);
        const int g = t >> 6;               // 0..3: rows [g*4, g*4+4)
        float acc[4];
        const float bias = b2[f];
        #pragma unroll
        for (int rr = 0; rr < 4; rr++) acc[rr] = bias;
        for (int d = 0; d < D1; d += 4) {
            const float w0 = W2[(d+0)*D2 + f];
            const float w1 = W2[(d+1)*D2 + f];
            const float w2_ = W2[(d+2)*D2 + f];
            const float w3 = W2[(d+3)*D2 + f];
            #pragma unroll
            for (int rr = 0; rr < 4; rr++) {
                const float4 h = *(const float4*)&sh1[(g*4+rr)*D1 + d]; // wave-broadcast
                acc[rr] = fmaf(h.x, w0, acc[rr]);
                acc[rr] = fmaf(h.y, w1, acc[rr]);
                acc[rr] = fmaf(h.z, w2_, acc[rr]);
                acc[rr] = fmaf(h.w, w3, acc[rr]);
            }
        }
        #pragma unroll
        for (int rr = 0; rr < 4; rr++)
            sh2[(g*4+rr)*D2 + f] = fmaxf(acc[rr], 0.0f);
    }
    __syncthreads();

    // layer 3: 16 rows x 52 (f>=50 written as 0 padding)
    for (int item = t; item < R1*KP; item += 256) {
        const int r = item / KP;
        const int f = item - r*KP;
        float acc = 0.0f;
        if (f < NC) {
            acc = b3[f];
            for (int d = 0; d < D2; d++)
                acc = fmaf(sh2[r*D2 + d], W3[d*NC + f], acc);
        }
        sz[item] = acc;
        z[(row0 + r)*KP + f] = acc;
    }
    __syncthreads();

    if (t < R1) {
        float s = 0.0f;
        #pragma unroll
        for (int k = 0; k < NC; k++) { const float v = sz[t*KP + k]; s = fmaf(v, v, s); }
        sq[row0 + t] = s;
    }
}

// ------- Kernel 2: fused pairwise dist -> exp(exp(-d/2)) -> softmax -> +eps renorm -------
// Block: 1024 threads = 8 groups of 128; group isub owns row i0+isub.
// Thread jt in group owns 32 consecutive j, e-values cached in 32 VGPRs.
__global__ __launch_bounds__(1024) void pair_kernel(
    const float* __restrict__ z, const float* __restrict__ sq,
    float* __restrict__ out)
{
    const int t = threadIdx.x;
    const int isub = t >> 7;              // 0..7 (wave-uniform)
    const int jt = t & 127;               // 0..127
    const int bpb = NN / TI;              // 512 blocks per batch
    const int b = blockIdx.x / bpb;
    const int i0 = (blockIdx.x - b*bpb) * TI;
    const int i = i0 + isub;
    const long zrow0 = (long)b * NN;

    __shared__ __align__(16) float szi[TI*KP];
    for (int k = t; k < TI*KP; k += 1024)
        szi[k] = z[(zrow0 + i0)*KP + k];
    __syncthreads();

    const float sqi = sq[zrow0 + i];
    const float4* zi4 = (const float4*)(szi + isub*KP);   // wave-uniform addr -> broadcast
    const int jbase = jt * 32;

    float cache[32];
    float rowsum = 0.0f;

    #pragma unroll
    for (int jj0 = 0; jj0 < 32; jj0 += 4) {
        const int j = jbase + jj0;
        const float4* zj0 = (const float4*)(z + (zrow0 + j + 0)*KP);
        const float4* zj1 = (const float4*)(z + (zrow0 + j + 1)*KP);
        const float4* zj2 = (const float4*)(z + (zrow0 + j + 2)*KP);
        const float4* zj3 = (const float4*)(z + (zrow0 + j + 3)*KP);
        float a0 = 0.f, a1 = 0.f, a2 = 0.f, a3 = 0.f;
        #pragma unroll
        for (int k = 0; k < KP/4; k++) {
            const float4 a  = zi4[k];
            const float4 p0 = zj0[k];
            const float4 p1 = zj1[k];
            const float4 p2 = zj2[k];
            const float4 p3 = zj3[k];
            a0 = fmaf(a.x, p0.x, fmaf(a.y, p0.y, fmaf(a.z, p0.z, fmaf(a.w, p0.w, a0))));
            a1 = fmaf(a.x, p1.x, fmaf(a.y, p1.y, fmaf(a.z, p1.z, fmaf(a.w, p1.w, a1))));
            a2 = fmaf(a.x, p2.x, fmaf(a.y, p2.y, fmaf(a.z, p2.z, fmaf(a.w, p2.w, a2))));
            a3 = fmaf(a.x, p3.x, fmaf(a.y, p3.y, fmaf(a.z, p3.z, fmaf(a.w, p3.w, a3))));
        }
        const float sq0 = sq[zrow0 + j + 0];
        const float sq1 = sq[zrow0 + j + 1];
        const float sq2 = sq[zrow0 + j + 2];
        const float sq3 = sq[zrow0 + j + 3];
        float d0 = fmaxf(sqi + sq0 - 2.0f*a0, 0.0f);
        float d1 = fmaxf(sqi + sq1 - 2.0f*a1, 0.0f);
        float d2 = fmaxf(sqi + sq2 - 2.0f*a2, 0.0f);
        float d3 = fmaxf(sqi + sq3 - 2.0f*a3, 0.0f);
        const float e0 = __expf(__expf(-0.5f*d0));
        const float e1 = __expf(__expf(-0.5f*d1));
        const float e2 = __expf(__expf(-0.5f*d2));
        const float e3 = __expf(__expf(-0.5f*d3));
        cache[jj0+0] = e0;
        cache[jj0+1] = e1;
        cache[jj0+2] = e2;
        cache[jj0+3] = e3;
        rowsum += (e0 + e1) + (e2 + e3);
    }

    // reduce rowsum across the 128-thread group (2 waves)
    #pragma unroll
    for (int off = 32; off > 0; off >>= 1)
        rowsum += __shfl_xor(rowsum, off, 64);
    __shared__ float wsum[16];
    const int wave = t >> 6, lane = t & 63;
    if (lane == 0) wsum[wave] = rowsum;
    __syncthreads();
    const float S = wsum[2*isub] + wsum[2*isub + 1];
    const float invS = 1.0f / S;
    const float renorm = 1.0f / (1.0f + (float)NN * 1e-6f);

    float* orow = out + ((long)(b*NN + i))*NN + jbase;
    #pragma unroll
    for (int q = 0; q < 8; q++) {
        float4 v;
        v.x = fmaf(cache[q*4+0], invS, 1e-6f) * renorm;
        v.y = fmaf(cache[q*4+1], invS, 1e-6f) * renorm;
        v.z = fmaf(cache[q*4+2], invS, 1e-6f) * renorm;
        v.w = fmaf(cache[q*4+3], invS, 1e-6f) * renorm;
        ((float4*)orow)[q] = v;
    }
}

extern "C" void kernel_launch(void* const* d_in, const int* in_sizes, int n_in,
                              void* d_out, int out_size, void* d_ws, size_t ws_size,
                              hipStream_t stream) {
    const float* emb = (const float*)d_in[0];
    const float* W1  = (const float*)d_in[1];
    const float* b1  = (const float*)d_in[2];
    const float* W2  = (const float*)d_in[3];
    const float* b2  = (const float*)d_in[4];
    const float* W3  = (const float*)d_in[5];
    const float* b3  = (const float*)d_in[6];
    float* out = (float*)d_out;

    float* z  = (float*)d_ws;                       // NB*NN*KP floats
    float* sq = z + (size_t)NB*NN*KP;               // NB*NN floats

    mlp_kernel<<<NB*NN/R1, 256, 0, stream>>>(emb, W1, b1, W2, b2, W3, b3, z, sq);
    pair_kernel<<<NB*(NN/TI), 1024, 0, stream>>>(z, sq, out);
}

// Round 2
// 406.009 us; speedup vs baseline: 7.0248x; 7.0248x over previous
//
#include <hip/hip_runtime.h>
#include <cstdint>

#define ED 256
#define D1 128
#define D2 64
#define NC 50
#define NB 4
#define NN 4096
#define R1 16      // rows per block, mlp kernel
#define TIB 8      // i-rows per block, pair kernel
#define JT 8       // j per thread, pair kernel
#define PTH 512    // threads, pair kernel

// ---------------- Kernel 1: MLP 256 -> 128 -> 64 -> 50, writes zT[b][k][n] + |z|^2 ----------------
__global__ __launch_bounds__(256) void mlp_kernel(
    const float* __restrict__ emb,
    const float* __restrict__ W1, const float* __restrict__ b1,
    const float* __restrict__ W2, const float* __restrict__ b2,
    const float* __restrict__ W3, const float* __restrict__ b3,
    float* __restrict__ zT, float* __restrict__ sq)
{
    __shared__ __align__(16) float se[R1*ED];
    __shared__ __align__(16) float sh1[R1*D1];
    __shared__ __align__(16) float sh2[R1*D2];
    __shared__ __align__(16) float sz[R1*NC];
    const int t = threadIdx.x;
    const long row0 = (long)blockIdx.x * R1;

    // stage 16 embedding rows (contiguous) into LDS, float4
    {
        const float4* g4 = (const float4*)(emb + row0*ED);
        float4* s4 = (float4*)se;
        #pragma unroll
        for (int k = 0; k < (R1*ED/4)/256; k++)
            s4[t + k*256] = g4[t + k*256];
    }
    __syncthreads();

    // layer 1: each thread = one f column, 8 rows
    {
        const int f = t & (D1-1);
        const int half = t >> 7;
        float acc[8];
        const float bias = b1[f];
        #pragma unroll
        for (int rr = 0; rr < 8; rr++) acc[rr] = bias;
        for (int d = 0; d < ED; d += 4) {
            const float w0 = W1[(d+0)*D1 + f];
            const float w1 = W1[(d+1)*D1 + f];
            const float w2 = W1[(d+2)*D1 + f];
            const float w3 = W1[(d+3)*D1 + f];
            #pragma unroll
            for (int rr = 0; rr < 8; rr++) {
                const float4 e = *(const float4*)&se[(half*8+rr)*ED + d];
                acc[rr] = fmaf(e.x, w0, acc[rr]);
                acc[rr] = fmaf(e.y, w1, acc[rr]);
                acc[rr] = fmaf(e.z, w2, acc[rr]);
                acc[rr] = fmaf(e.w, w3, acc[rr]);
            }
        }
        #pragma unroll
        for (int rr = 0; rr < 8; rr++)
            sh1[(half*8+rr)*D1 + f] = fmaxf(acc[rr], 0.0f);
    }
    __syncthreads();

    // layer 2: each thread = one f (0..63), 4 rows
    {
        const int f = t & (D2-1);
        const int g = t >> 6;
        float acc[4];
        const float bias = b2[f];
        #pragma unroll
        for (int rr = 0; rr < 4; rr++) acc[rr] = bias;
        for (int d = 0; d < D1; d += 4) {
            const float w0 = W2[(d+0)*D2 + f];
            const float w1 = W2[(d+1)*D2 + f];
            const float w2_ = W2[(d+2)*D2 + f];
            const float w3 = W2[(d+3)*D2 + f];
            #pragma unroll
            for (int rr = 0; rr < 4; rr++) {
                const float4 h = *(const float4*)&sh1[(g*4+rr)*D1 + d];
                acc[rr] = fmaf(h.x, w0, acc[rr]);
                acc[rr] = fmaf(h.y, w1, acc[rr]);
                acc[rr] = fmaf(h.z, w2_, acc[rr]);
                acc[rr] = fmaf(h.w, w3, acc[rr]);
            }
        }
        #pragma unroll
        for (int rr = 0; rr < 4; rr++)
            sh2[(g*4+rr)*D2 + f] = fmaxf(acc[rr], 0.0f);
    }
    __syncthreads();

    // layer 3: 16 rows x 50 -> zT[b][f][n] (transposed for pair kernel coalescing)
    const int bb = (int)(row0 / NN);
    const int n0 = (int)(row0 - (long)bb*NN);
    for (int item = t; item < R1*NC; item += 256) {
        const int r = item / NC;
        const int f = item - r*NC;
        float acc = b3[f];
        for (int d = 0; d < D2; d++)
            acc = fmaf(sh2[r*D2 + d], W3[d*NC + f], acc);
        sz[r*NC + f] = acc;
        zT[((size_t)bb*NC + f)*NN + n0 + r] = acc;
    }
    __syncthreads();

    if (t < R1) {
        float s = 0.0f;
        #pragma unroll
        for (int k = 0; k < NC; k++) { const float v = sz[t*NC + k]; s = fmaf(v, v, s); }
        sq[row0 + t] = s;
    }
}

// ------- Kernel 2: fused pairwise dist -> exp(exp(-d/2)) -> softmax -> +eps renorm -------
// Block: 512 threads, TIB=8 i-rows, full j-row (4096). Thread t owns j = t*4+{0..3} and
// j = t*4+2048+{0..3}: every global load/store is a perfectly coalesced wave-contiguous float4.
__global__ __launch_bounds__(PTH) void pair_kernel(
    const float* __restrict__ zT, const float* __restrict__ sq,
    float* __restrict__ out)
{
    const int t = threadIdx.x;
    const int b = blockIdx.x >> 9;               // / (NN/TIB) = 512
    const int i0 = (blockIdx.x & 511) * TIB;

    __shared__ __align__(16) float szi[NC][TIB]; // z_i fragments, k-major
    __shared__ float wsum[PTH/64][TIB];
    __shared__ float sS[TIB];

    const float* ztb = zT + (size_t)b * NC * NN;

    // stage z_i (8 rows x 50 k) into LDS — tiny gather from L2
    for (int idx = t; idx < NC*TIB; idx += PTH) {
        const int k = idx >> 3, ii = idx & 7;
        szi[k][ii] = ztb[(size_t)k*NN + i0 + ii];
    }
    __syncthreads();

    float acc[TIB][JT];
    #pragma unroll
    for (int ii = 0; ii < TIB; ii++)
        #pragma unroll
        for (int jj = 0; jj < JT; jj++) acc[ii][jj] = 0.0f;

    const int j0 = t * 4;
    #pragma unroll 5
    for (int k = 0; k < NC; k++) {
        const float4 zj0 = *(const float4*)(ztb + (size_t)k*NN + j0);          // coalesced 1KB/wave
        const float4 zj1 = *(const float4*)(ztb + (size_t)k*NN + j0 + 2048);   // coalesced 1KB/wave
        const float4 zia = *(const float4*)&szi[k][0];                         // LDS broadcast
        const float4 zib = *(const float4*)&szi[k][4];
        const float zi[8] = {zia.x, zia.y, zia.z, zia.w, zib.x, zib.y, zib.z, zib.w};
        const float zj[8] = {zj0.x, zj0.y, zj0.z, zj0.w, zj1.x, zj1.y, zj1.z, zj1.w};
        #pragma unroll
        for (int ii = 0; ii < TIB; ii++)
            #pragma unroll
            for (int jj = 0; jj < JT; jj++)
                acc[ii][jj] = fmaf(zi[ii], zj[jj], acc[ii][jj]);
    }

    const float* sqb = sq + (size_t)b * NN;
    float sqi[TIB];
    #pragma unroll
    for (int ii = 0; ii < TIB; ii++) sqi[ii] = sqb[i0 + ii];   // broadcast, L1
    const float4 sja = *(const float4*)(sqb + j0);
    const float4 sjb = *(const float4*)(sqb + j0 + 2048);
    const float sqj[8] = {sja.x, sja.y, sja.z, sja.w, sjb.x, sjb.y, sjb.z, sjb.w};

    // dist -> e = exp(exp(-d/2)) in place, accumulate row sums
    float rsum[TIB];
    #pragma unroll
    for (int ii = 0; ii < TIB; ii++) {
        float s = 0.0f;
        #pragma unroll
        for (int jj = 0; jj < JT; jj++) {
            const float d = fmaxf(sqi[ii] + sqj[jj] - 2.0f*acc[ii][jj], 0.0f);
            const float e = __expf(__expf(-0.5f*d));
            acc[ii][jj] = e;
            s += e;
        }
        rsum[ii] = s;
    }

    // reduce rsum[8] across the block: wave shfl -> LDS -> final
    #pragma unroll
    for (int off = 32; off; off >>= 1)
        #pragma unroll
        for (int ii = 0; ii < TIB; ii++)
            rsum[ii] += __shfl_xor(rsum[ii], off, 64);
    const int wave = t >> 6, lane = t & 63;
    if (lane == 0) {
        #pragma unroll
        for (int ii = 0; ii < TIB; ii++) wsum[wave][ii] = rsum[ii];
    }
    __syncthreads();
    if (t < TIB) {
        float s = 0.0f;
        #pragma unroll
        for (int w = 0; w < PTH/64; w++) s += wsum[w][t];
        sS[t] = s;
    }
    __syncthreads();

    const float rn = 1.0f / (1.0f + (float)NN * 1e-6f);
    const float c = 1e-6f * rn;
    float* ob = out + ((size_t)(b*NN + i0)) * NN;
    #pragma unroll
    for (int ii = 0; ii < TIB; ii++) {
        const float is = rn / sS[ii];   // broadcast LDS read
        float4 v0, v1;
        v0.x = fmaf(acc[ii][0], is, c);
        v0.y = fmaf(acc[ii][1], is, c);
        v0.z = fmaf(acc[ii][2], is, c);
        v0.w = fmaf(acc[ii][3], is, c);
        v1.x = fmaf(acc[ii][4], is, c);
        v1.y = fmaf(acc[ii][5], is, c);
        v1.z = fmaf(acc[ii][6], is, c);
        v1.w = fmaf(acc[ii][7], is, c);
        *(float4*)(ob + (size_t)ii*NN + j0) = v0;          // coalesced 1KB/wave
        *(float4*)(ob + (size_t)ii*NN + j0 + 2048) = v1;   // coalesced 1KB/wave
    }
}

extern "C" void kernel_launch(void* const* d_in, const int* in_sizes, int n_in,
                              void* d_out, int out_size, void* d_ws, size_t ws_size,
                              hipStream_t stream) {
    const float* emb = (const float*)d_in[0];
    const float* W1  = (const float*)d_in[1];
    const float* b1  = (const float*)d_in[2];
    const float* W2  = (const float*)d_in[3];
    const float* b2  = (const float*)d_in[4];
    const float* W3  = (const float*)d_in[5];
    const float* b3  = (const float*)d_in[6];
    float* out = (float*)d_out;

    float* zT = (float*)d_ws;                       // NB*NC*NN floats (transposed)
    float* sq = zT + (size_t)NB*NC*NN;              // NB*NN floats

    mlp_kernel<<<NB*NN/R1, 256, 0, stream>>>(emb, W1, b1, W2, b2, W3, b3, zT, sq);
    pair_kernel<<<NB*(NN/TIB), PTH, 0, stream>>>(zT, sq, out);
}